// Round 4
// baseline (263.975 us; speedup 1.0000x reference)
//
#include <hip/hip_runtime.h>

// Performer feature map: out[row][m] = exp( sum_k x[row][k]/scale * W[m][k] ) / sqrt(M)
// rows = B*H*L = 262144, K = D = 128, N = M = 128. Memory-bound (32 FLOP/byte).
//
// R4: swapped-operand MFMA + full-line nt-store epilogue + 4 blocks/CU.
//   Evidence: R0 (128 B/row/instr stores) ~75 us; R1 (64 B nt) 118 us, WRITE 220 MB;
//   R3 (64 B plain) 107 us, WRITE 184 MB, FETCH 172 MB. 64 B store segments do NOT
//   merge into full lines at L2->HBM (partial-line eviction RMW: write amp + RMW
//   fetches). Fix: per-wave LDS quarter-tile transpose so every global store
//   instruction writes 8 rows x 128 B contiguous, nontemporal (no RMW, no L2 sweep).
//   LDS budget: Wb XOR-swizzled unpadded 32768 B + Ob 4x(16x32 f32) 8192 B
//   = 40960 B exactly -> 4 blocks/CU (16 waves/CU).

typedef __attribute__((ext_vector_type(8))) short bf16x8;   // MFMA A/B frag (4 VGPRs)
typedef __attribute__((ext_vector_type(4))) float f32x4;    // MFMA C/D frag + 16B vec ld/st
typedef __attribute__((ext_vector_type(4))) short short4v;

__device__ __forceinline__ short f2bf(float f) {
    // round-to-nearest-even fp32 -> bf16 (finite gaussian inputs; no NaN path)
    union { float f; unsigned u; } v; v.f = f;
    return (short)((v.u + 0x7fffu + ((v.u >> 16) & 1u)) >> 16);
}

__global__ __launch_bounds__(256, 4)
void performer_kernel(const float* __restrict__ x,
                      const float* __restrict__ Wf,
                      float* __restrict__ out,
                      int n_chunks) {   // chunk = 64 rows (4 waves x 16 rows)
    // Wb: 128x128 shorts, XOR swizzle on short-col: scol = col ^ ((row&7)<<3).
    //   Granule 8 shorts = 16 B = b128 read width -> reads stay contiguous.
    //   b128 frag reads: 8 lanes per 4-bank group = hw minimum (conflict-free).
    __shared__ short Wb[128 * 128];      // 32768 B
    // Ob: per-wave 16x32 f32 quarter tile, XOR swizzle: col4 ^= (row&7) (4-float granule).
    __shared__ float Ob[4 * 16 * 32];    // 8192 B

    const int tid = threadIdx.x;

    // ---- Stage W -> LDS as bf16, scale 1/128^0.25 folded in. Coalesced float4 reads. ----
    {
        const float inv_scale = 0.29730177875068026f;  // 128^-0.25
        #pragma unroll
        for (int i = 0; i < 16; ++i) {
            int idx = i * 256 + tid;          // float4 index, 4096 total (128x128 fp32)
            int row = idx >> 5;
            int cs  = (idx & 31) << 2;        // short-col of this 4-short piece
            f32x4 v = reinterpret_cast<const f32x4*>(Wf)[idx];
            short4v s;
            s.x = f2bf(v.x * inv_scale);
            s.y = f2bf(v.y * inv_scale);
            s.z = f2bf(v.z * inv_scale);
            s.w = f2bf(v.w * inv_scale);
            // XOR affects bits >=3 only; cs&7 in {0,4} preserved within the 16 B group
            *reinterpret_cast<short4v*>(&Wb[row * 128 + (cs ^ ((row & 7) << 3))]) = s;
        }
    }
    __syncthreads();

    const int wave = tid >> 6;
    const int lane = tid & 63;
    const int m    = lane & 15;      // X-frag row (x-row within 16-tile); W-frag feature row
    const int quad = lane >> 4;      // k-subblock select; D feature-quad
    const int r8   = lane >> 3;      // epilogue readback: row within 8-group
    const int c8   = lane & 7;       // epilogue readback: 16 B chunk within 128 B
    float* obuf = &Ob[wave * 16 * 32];
    const float inv_sqrt_m = 0.08838834764831845f;  // 1/sqrt(128)

    for (int chunk = blockIdx.x; chunk < n_chunks; chunk += gridDim.x) {
        const long row0 = (long)chunk * 64 + wave * 16;
        const float* xrow = x + (row0 + m) * 128 + quad * 8;

        // ---- X tile: 4 k-steps x 8 floats/lane, 32 B contiguous per lane.
        //      Adjacent instr pair covers each 128 B line fully. ----
        f32x4 av[4][2];
        #pragma unroll
        for (int ks = 0; ks < 4; ++ks) {
            const f32x4* p = reinterpret_cast<const f32x4*>(xrow + ks * 32);
            av[ks][0] = p[0];
            av[ks][1] = p[1];
        }
        bf16x8 af[4];
        #pragma unroll
        for (int ks = 0; ks < 4; ++ks) {
            af[ks][0] = f2bf(av[ks][0].x);
            af[ks][1] = f2bf(av[ks][0].y);
            af[ks][2] = f2bf(av[ks][0].z);
            af[ks][3] = f2bf(av[ks][0].w);
            af[ks][4] = f2bf(av[ks][1].x);
            af[ks][5] = f2bf(av[ks][1].y);
            af[ks][6] = f2bf(av[ks][1].z);
            af[ks][7] = f2bf(av[ks][1].w);
        }

        // ---- 8 feature-tiles of 16: MFMA with SWAPPED operands (A=W, B=X) ----
        // D[feature][xrow]: col = lane&15 = xrow m, row = quad*4+r = feature in tile.
        f32x4 acc[8];
        #pragma unroll
        for (int nt = 0; nt < 8; ++nt) {
            f32x4 a = {0.f, 0.f, 0.f, 0.f};
            #pragma unroll
            for (int ks = 0; ks < 4; ++ks) {
                bf16x8 wf = *reinterpret_cast<const bf16x8*>(
                    &Wb[(nt * 16 + m) * 128 + ((ks * 32 + quad * 8) ^ ((m & 7) << 3))]);
                a = __builtin_amdgcn_mfma_f32_16x16x32_bf16(wf, af[ks], a, 0, 0, 0);
            }
            acc[nt] = a;
        }

        // ---- Epilogue: 4 quarters of 32 features. Per quarter: exp -> LDS 16x32
        //      tile (XOR-swizzled) -> read back 16 B/lane -> nt store 8 rows x 128 B
        //      contiguous per instruction (full L2 lines: no RMW). ----
        float* obase = out + row0 * 128;
        #pragma unroll
        for (int G = 0; G < 4; ++G) {
            #pragma unroll
            for (int half = 0; half < 2; ++half) {      // nt = 2G + half
                const int nt = 2 * G + half;
                f32x4 v;
                #pragma unroll
                for (int r = 0; r < 4; ++r)
                    v[r] = __expf(acc[nt][r]) * inv_sqrt_m;
                // local feature lf = half*16 + quad*4 + r; store at lf ^ ((m&7)<<2)
                const int col = (half * 16 + quad * 4) ^ ((m & 7) << 2);
                *reinterpret_cast<f32x4*>(&obuf[m * 32 + col]) = v;
            }
            // same-wave LDS RAW: compiler inserts lgkmcnt waits
            #pragma unroll
            for (int H = 0; H < 2; ++H) {
                const int row = H * 8 + r8;              // row&7 == r8
                f32x4 v = *reinterpret_cast<const f32x4*>(
                    &obuf[row * 32 + ((c8 * 4) ^ (r8 << 2))]);
                __builtin_nontemporal_store(v, reinterpret_cast<f32x4*>(
                    &obase[row * 128 + G * 32 + c8 * 4]));
            }
        }
    }
}

extern "C" void kernel_launch(void* const* d_in, const int* in_sizes, int n_in,
                              void* d_out, int out_size, void* d_ws, size_t ws_size,
                              hipStream_t stream) {
    const float* x  = (const float*)d_in[0];   // (B,H,L,D) fp32
    const float* Wf = (const float*)d_in[1];   // (M,D) fp32
    float* out = (float*)d_out;                // (B,H,L,M) fp32

    const int rows = out_size / 128;           // 262144
    const int n_chunks = rows / 64;            // 4096

    performer_kernel<<<dim3(1024), dim3(256), 0, stream>>>(x, Wf, out, n_chunks);
}